// Round 3
// baseline (4115.253 us; speedup 1.0000x reference)
//
#include <hip/hip_runtime.h>
#include <cstdint>

typedef unsigned short u16;
typedef __attribute__((ext_vector_type(8))) short short8;   // bf16x8 MFMA frag
typedef __attribute__((ext_vector_type(4))) float f32x4;    // fp32x4 accumulator

#define SEQ     2048
#define NHEADS  32
#define NKV     8
#define HD      64
#define DM      2048
#define MROWS   4096   // BATCH * SEQ

__device__ __forceinline__ float b2f(unsigned int u) {
    return __builtin_bit_cast(float, u << 16);
}
__device__ __forceinline__ u16 f2b(float f) {
    unsigned int u = __builtin_bit_cast(unsigned int, f);
    return (u16)((u + 0x7fffu + ((u >> 16) & 1u)) >> 16);   // RNE
}

// ------------------------------------------------------------- f32 -> bf16
__global__ __launch_bounds__(256) void cvt_f32_bf16(
    const float* __restrict__ in, u16* __restrict__ out, int n4) {
    int i = blockIdx.x * 256 + threadIdx.x;
    if (i < n4) {
        float4 v = ((const float4*)in)[i];
        ushort4 o;
        o.x = f2b(v.x); o.y = f2b(v.y); o.z = f2b(v.z); o.w = f2b(v.w);
        ((ushort4*)out)[i] = o;
    }
}

// ------------------------------------------------------------- RoPE tables
// cosT/sinT: [SEQ][32] fp32, accurate sincosf (full range reduction; the
// native v_sin path is undefined past +-256 revolutions).
__global__ __launch_bounds__(256) void rope_table_kernel(
    float* __restrict__ cosT, float* __restrict__ sinT) {
    int idx = blockIdx.x * 256 + threadIdx.x;     // 65536 = 2048*32
    int s  = idx >> 5;
    int dl = idx & 31;
    float inv_freq = exp2f((float)dl * -0.41524101186092025f); // 10000^(-dl/32)
    float ang = (float)s * inv_freq;
    float sn, cs;
    sincosf(ang, &sn, &cs);
    cosT[idx] = cs;
    sinT[idx] = sn;
}

// ------------------------------------------------- transpose + downcast
// in: K x N (row-major, f32) -> out: N x K (row-major, bf16)
__global__ __launch_bounds__(256) void transpose_f32_bf16(
    const float* __restrict__ in, u16* __restrict__ out, int K, int N) {
    __shared__ float tile[32][33];
    int n0 = blockIdx.x * 32, k0 = blockIdx.y * 32;
    int tx = threadIdx.x, ty = threadIdx.y;   // 32 x 8
    for (int r = ty; r < 32; r += 8)
        tile[r][tx] = in[(size_t)(k0 + r) * N + n0 + tx];
    __syncthreads();
    for (int r = ty; r < 32; r += 8)
        out[(size_t)(n0 + r) * K + k0 + tx] = f2b(tile[tx][r]);
}

// ---------------------------------------------------------------- GEMM
// C[M x N] = A[M x K] @ B  where BT is B^T (N x K row-major), bf16 inputs,
// fp32 accumulate via mfma_f32_16x16x32_bf16.
// Block: 256 thr = 4 waves. Block tile 128(M) x 64(N). Wave w: rows [32w,32w+32).
// ROPE=1: N-tile (64) == one head; rotary with position s = row % SEQ.
// F32OUT=1: write float32 C (final projection); else bf16.
template <int ROPE, int F32OUT>
__global__ __launch_bounds__(256) void gemm_bt(
    const u16* __restrict__ A, const u16* __restrict__ BT,
    u16* __restrict__ C16, float* __restrict__ C32,
    int M, int N, int K,
    const float* __restrict__ cosT, const float* __restrict__ sinT) {
    constexpr int BM = 128, BN = 64, BK = 32, LDS_K = 40;  // pad 32->40 (16B-aligned)
    __shared__ __align__(16) u16 As[BM * LDS_K];
    __shared__ __align__(16) u16 Bs[BN * LDS_K];

    const int tid  = threadIdx.x;
    const int wid  = tid >> 6;
    const int lane = tid & 63;
    const int quad = lane >> 4;
    const int l16  = lane & 15;
    const int rowBase = blockIdx.y * BM;
    const int colBase = blockIdx.x * BN;

    // staging coords: each thread moves one 16B chunk (8 bf16) per row-block
    const int sR = tid >> 2;          // 0..63
    const int sC = (tid & 3) * 8;     // 0,8,16,24

    f32x4 acc[2][4] = {};

    for (int k0 = 0; k0 < K; k0 += BK) {
        *(short8*)&As[sR * LDS_K + sC] =
            *(const short8*)&A[(size_t)(rowBase + sR) * K + k0 + sC];
        *(short8*)&As[(64 + sR) * LDS_K + sC] =
            *(const short8*)&A[(size_t)(rowBase + 64 + sR) * K + k0 + sC];
        *(short8*)&Bs[sR * LDS_K + sC] =
            *(const short8*)&BT[(size_t)(colBase + sR) * K + k0 + sC];
        __syncthreads();

        short8 a[2], b[4];
#pragma unroll
        for (int mt = 0; mt < 2; ++mt)
            a[mt] = *(const short8*)&As[(wid * 32 + mt * 16 + l16) * LDS_K + quad * 8];
#pragma unroll
        for (int ct = 0; ct < 4; ++ct)
            b[ct] = *(const short8*)&Bs[(ct * 16 + l16) * LDS_K + quad * 8];
#pragma unroll
        for (int mt = 0; mt < 2; ++mt)
#pragma unroll
            for (int ct = 0; ct < 4; ++ct)
                acc[mt][ct] = __builtin_amdgcn_mfma_f32_16x16x32_bf16(
                    a[mt], b[ct], acc[mt][ct], 0, 0, 0);
        __syncthreads();
    }

    // epilogue: D row = quad*4 + r (+16*mt +32*wid), col = ct*16 + l16
    const int wRow = rowBase + wid * 32;
#pragma unroll
    for (int mt = 0; mt < 2; ++mt) {
#pragma unroll
        for (int r = 0; r < 4; ++r) {
            const int R = wRow + mt * 16 + quad * 4 + r;
            if (F32OUT) {
                float* crow = C32 + (size_t)R * N + colBase;
#pragma unroll
                for (int ct = 0; ct < 4; ++ct)
                    crow[ct * 16 + l16] = acc[mt][ct][r];
            } else if (ROPE) {
                u16* crow = C16 + (size_t)R * N + colBase;
                const int s = R & (SEQ - 1);
#pragma unroll
                for (int ct = 0; ct < 2; ++ct) {
                    const int dl = ct * 16 + l16;           // 0..31
                    float lo = acc[mt][ct][r];              // q[d]
                    float hi = acc[mt][ct + 2][r];          // q[d+32]
                    float cs = cosT[s * 32 + dl];
                    float sn = sinT[s * 32 + dl];
                    crow[dl]      = f2b(lo * cs - hi * sn);
                    crow[dl + 32] = f2b(hi * cs + lo * sn);
                }
            } else {
                u16* crow = C16 + (size_t)R * N + colBase;
#pragma unroll
                for (int ct = 0; ct < 4; ++ct)
                    crow[ct * 16 + l16] = f2b(acc[mt][ct][r]);
            }
        }
    }
}

// ---------------------------------------------------------------- attention
// One block (256 thr) per (b, h, query-row). Two-pass softmax, scores in LDS.
__device__ __forceinline__ float waveRedMax(float x) {
#pragma unroll
    for (int off = 32; off > 0; off >>= 1)
        x = fmaxf(x, __shfl_down(x, off, 64));
    return x;
}
__device__ __forceinline__ float waveRedSum(float x) {
#pragma unroll
    for (int off = 32; off > 0; off >>= 1)
        x += __shfl_down(x, off, 64);
    return x;
}

__global__ __launch_bounds__(256) void attn_kernel(
    const u16* __restrict__ Q, const u16* __restrict__ K,
    const u16* __restrict__ V, u16* __restrict__ Y) {
    __shared__ float scores[SEQ];
    __shared__ float red[4];
    __shared__ float yred[256];

    const int i = blockIdx.x;            // query row
    const int h = blockIdx.y;            // q head
    const int b = blockIdx.z;
    const int h2 = h >> 2;               // kv head (GQA 4:1)
    const int tid = threadIdx.x;
    const int nk = i + 1;

    // q row -> registers (fp32)
    float qr[HD];
    {
        const uint4* q4 = (const uint4*)(Q + ((size_t)(b * SEQ + i) * (NHEADS * HD) + h * HD));
#pragma unroll
        for (int m = 0; m < 8; ++m) {
            uint4 w = q4[m];
            qr[8*m+0] = b2f(w.x & 0xffffu); qr[8*m+1] = b2f(w.x >> 16);
            qr[8*m+2] = b2f(w.y & 0xffffu); qr[8*m+3] = b2f(w.y >> 16);
            qr[8*m+4] = b2f(w.z & 0xffffu); qr[8*m+5] = b2f(w.z >> 16);
            qr[8*m+6] = b2f(w.w & 0xffffu); qr[8*m+7] = b2f(w.w >> 16);
        }
    }

    const u16* kbase = K + (size_t)b * SEQ * (NKV * HD) + h2 * HD;
    float lmax = -3e38f;
    for (int j = tid; j < nk; j += 256) {
        const uint4* k4 = (const uint4*)(kbase + (size_t)j * (NKV * HD));
        float acc = 0.f;
#pragma unroll
        for (int m = 0; m < 8; ++m) {
            uint4 w = k4[m];
            acc += qr[8*m+0]*b2f(w.x & 0xffffu) + qr[8*m+1]*b2f(w.x >> 16)
                 + qr[8*m+2]*b2f(w.y & 0xffffu) + qr[8*m+3]*b2f(w.y >> 16)
                 + qr[8*m+4]*b2f(w.z & 0xffffu) + qr[8*m+5]*b2f(w.z >> 16)
                 + qr[8*m+6]*b2f(w.w & 0xffffu) + qr[8*m+7]*b2f(w.w >> 16);
        }
        acc *= 0.125f;                    // 1/sqrt(64)
        scores[j] = acc;
        lmax = fmaxf(lmax, acc);
    }

    // block max
    lmax = waveRedMax(lmax);
    __syncthreads();
    if ((tid & 63) == 0) red[tid >> 6] = lmax;
    __syncthreads();
    const float m = fmaxf(fmaxf(red[0], red[1]), fmaxf(red[2], red[3]));

    float lsum = 0.f;
    for (int j = tid; j < nk; j += 256) {
        float e = __expf(scores[j] - m);
        scores[j] = e;
        lsum += e;
    }
    lsum = waveRedSum(lsum);
    __syncthreads();
    if ((tid & 63) == 0) red[tid >> 6] = lsum;
    __syncthreads();
    const float denom = red[0] + red[1] + red[2] + red[3];

    // PV: thread t handles dim d = t&63, key-stripe g = t>>6
    const int d = tid & 63, g = tid >> 6;
    const u16* vbase = V + (size_t)b * SEQ * (NKV * HD) + h2 * HD + d;
    float acc = 0.f;
    for (int j = g; j < nk; j += 4)
        acc += scores[j] * b2f((unsigned int)vbase[(size_t)j * (NKV * HD)]);
    yred[tid] = acc;
    __syncthreads();
    if (tid < 64) {
        float sum = yred[tid] + yred[tid + 64] + yred[tid + 128] + yred[tid + 192];
        Y[(size_t)(b * SEQ + i) * (NHEADS * HD) + h * HD + tid] = f2b(sum / denom);
    }
}

// ---------------------------------------------------------------- launch
extern "C" void kernel_launch(void* const* d_in, const int* in_sizes, int n_in,
                              void* d_out, int out_size, void* d_ws, size_t ws_size,
                              hipStream_t stream) {
    // Inputs are FLOAT32 per the reference (f32-as-bf16 misread was the
    // round-1/2 NaN source: random low-mantissa u16 patterns decode to
    // NaN/inf with p~1/256, guaranteeing NaN dot products).
    const float* x  = (const float*)d_in[0];
    const float* Wq = (const float*)d_in[1];
    const float* Wk = (const float*)d_in[2];
    const float* Wv = (const float*)d_in[3];
    const float* Wo = (const float*)d_in[4];
    float* out = (float*)d_out;   // f32 output

    char* ws = (char*)d_ws;
    u16*  xb   = (u16*)(ws);                     // 16 MB  4096x2048 bf16
    u16*  WqT  = (u16*)(ws + 16777216);          //  8 MB  2048x2048
    u16*  WkT  = (u16*)(ws + 25165824);          //  2 MB   512x2048
    u16*  WvT  = (u16*)(ws + 27262976);          //  2 MB   512x2048
    u16*  WoT  = (u16*)(ws + 29360128);          //  8 MB  2048x2048
    u16*  Qb   = (u16*)(ws + 37748736);          // 16 MB  4096x2048 (roped)
    u16*  Kb   = (u16*)(ws + 54525952);          //  4 MB  4096x512  (roped)
    u16*  Vb   = (u16*)(ws + 58720256);          //  4 MB  4096x512
    u16*  Yb   = (u16*)(ws + 62914560);          // 16 MB  4096x2048
    float* cosT = (float*)(ws + 79691776);       // 256 KB 2048x32
    float* sinT = (float*)(ws + 79953920);       // 256 KB

    rope_table_kernel<<<dim3(65536 / 256), 256, 0, stream>>>(cosT, sinT);

    cvt_f32_bf16<<<dim3(MROWS * DM / 4 / 256), 256, 0, stream>>>(x, xb, MROWS * DM / 4);

    dim3 tb(32, 8);
    transpose_f32_bf16<<<dim3(2048/32, 2048/32), tb, 0, stream>>>(Wq, WqT, 2048, 2048);
    transpose_f32_bf16<<<dim3( 512/32, 2048/32), tb, 0, stream>>>(Wk, WkT, 2048,  512);
    transpose_f32_bf16<<<dim3( 512/32, 2048/32), tb, 0, stream>>>(Wv, WvT, 2048,  512);
    transpose_f32_bf16<<<dim3(2048/32, 2048/32), tb, 0, stream>>>(Wo, WoT, 2048, 2048);

    gemm_bt<1,0><<<dim3(2048/64, MROWS/128), 256, 0, stream>>>(xb, WqT, Qb, nullptr, MROWS, 2048, 2048, cosT, sinT);
    gemm_bt<1,0><<<dim3( 512/64, MROWS/128), 256, 0, stream>>>(xb, WkT, Kb, nullptr, MROWS,  512, 2048, cosT, sinT);
    gemm_bt<0,0><<<dim3( 512/64, MROWS/128), 256, 0, stream>>>(xb, WvT, Vb, nullptr, MROWS,  512, 2048, nullptr, nullptr);

    attn_kernel<<<dim3(SEQ, NHEADS, 2), 256, 0, stream>>>(Qb, Kb, Vb, Yb);

    gemm_bt<0,1><<<dim3(2048/64, MROWS/128), 256, 0, stream>>>(Yb, WoT, nullptr, out, MROWS, 2048, 2048, nullptr, nullptr);
}

// Round 5
// 587.619 us; speedup vs baseline: 7.0033x; 7.0033x over previous
//
#include <hip/hip_runtime.h>
#include <cstdint>

typedef unsigned short u16;
typedef __attribute__((ext_vector_type(8))) short short8;   // bf16x8 MFMA frag
typedef __attribute__((ext_vector_type(4))) float f32x4;    // fp32x4 accumulator

#define SEQ     2048
#define NHEADS  32
#define NKV     8
#define HD      64
#define DM      2048
#define MROWS   4096   // BATCH * SEQ

__device__ __forceinline__ float b2f(unsigned int u) {
    return __builtin_bit_cast(float, u << 16);
}
__device__ __forceinline__ u16 f2b(float f) {
    unsigned int u = __builtin_bit_cast(unsigned int, f);
    return (u16)((u + 0x7fffu + ((u >> 16) & 1u)) >> 16);   // RNE
}

// ------------------------------------------------------------- f32 -> bf16
__global__ __launch_bounds__(256) void cvt_f32_bf16(
    const float* __restrict__ in, u16* __restrict__ out, int n4) {
    int i = blockIdx.x * 256 + threadIdx.x;
    if (i < n4) {
        float4 v = ((const float4*)in)[i];
        ushort4 o;
        o.x = f2b(v.x); o.y = f2b(v.y); o.z = f2b(v.z); o.w = f2b(v.w);
        ((ushort4*)out)[i] = o;
    }
}

// ------------------------------------------------------------- RoPE tables
__global__ __launch_bounds__(256) void rope_table_kernel(
    float* __restrict__ cosT, float* __restrict__ sinT) {
    int idx = blockIdx.x * 256 + threadIdx.x;     // 65536 = 2048*32
    int s  = idx >> 5;
    int dl = idx & 31;
    float inv_freq = exp2f((float)dl * -0.41524101186092025f); // 10000^(-dl/32)
    float ang = (float)s * inv_freq;
    float sn, cs;
    sincosf(ang, &sn, &cs);                        // accurate (range-reduced)
    cosT[idx] = cs;
    sinT[idx] = sn;
}

// ------------------------------------------------- transpose + downcast
__global__ __launch_bounds__(256) void transpose_f32_bf16(
    const float* __restrict__ in, u16* __restrict__ out, int K, int N) {
    __shared__ float tile[32][33];
    int n0 = blockIdx.x * 32, k0 = blockIdx.y * 32;
    int tx = threadIdx.x, ty = threadIdx.y;   // 32 x 8
    for (int r = ty; r < 32; r += 8)
        tile[r][tx] = in[(size_t)(k0 + r) * N + n0 + tx];
    __syncthreads();
    for (int r = ty; r < 32; r += 8)
        out[(size_t)(n0 + r) * K + k0 + tx] = f2b(tile[tx][r]);
}

// ---------------------------------------------------------------- GEMM
// C[M x N] = A[M x K] @ B, BT = B^T (N x K row-major), bf16 in, f32 acc.
// ROPE=1: N-tile == one head; rotary with s = row % SEQ; multiply by `scale`
// (Q path folds 1/sqrt(64) here). F32OUT=1: write f32 (final projection).
template <int ROPE, int F32OUT>
__global__ __launch_bounds__(256) void gemm_bt(
    const u16* __restrict__ A, const u16* __restrict__ BT,
    u16* __restrict__ C16, float* __restrict__ C32,
    int M, int N, int K,
    const float* __restrict__ cosT, const float* __restrict__ sinT,
    float scale) {
    constexpr int BM = 128, BN = 64, BK = 32, LDS_K = 40;
    __shared__ __align__(16) u16 As[BM * LDS_K];
    __shared__ __align__(16) u16 Bs[BN * LDS_K];

    const int tid  = threadIdx.x;
    const int wid  = tid >> 6;
    const int lane = tid & 63;
    const int quad = lane >> 4;
    const int l16  = lane & 15;
    const int rowBase = blockIdx.y * BM;
    const int colBase = blockIdx.x * BN;

    const int sR = tid >> 2;          // 0..63
    const int sC = (tid & 3) * 8;     // 0,8,16,24

    f32x4 acc[2][4] = {};

    for (int k0 = 0; k0 < K; k0 += BK) {
        *(short8*)&As[sR * LDS_K + sC] =
            *(const short8*)&A[(size_t)(rowBase + sR) * K + k0 + sC];
        *(short8*)&As[(64 + sR) * LDS_K + sC] =
            *(const short8*)&A[(size_t)(rowBase + 64 + sR) * K + k0 + sC];
        *(short8*)&Bs[sR * LDS_K + sC] =
            *(const short8*)&BT[(size_t)(colBase + sR) * K + k0 + sC];
        __syncthreads();

        short8 a[2], b[4];
#pragma unroll
        for (int mt = 0; mt < 2; ++mt)
            a[mt] = *(const short8*)&As[(wid * 32 + mt * 16 + l16) * LDS_K + quad * 8];
#pragma unroll
        for (int ct = 0; ct < 4; ++ct)
            b[ct] = *(const short8*)&Bs[(ct * 16 + l16) * LDS_K + quad * 8];
#pragma unroll
        for (int mt = 0; mt < 2; ++mt)
#pragma unroll
            for (int ct = 0; ct < 4; ++ct)
                acc[mt][ct] = __builtin_amdgcn_mfma_f32_16x16x32_bf16(
                    a[mt], b[ct], acc[mt][ct], 0, 0, 0);
        __syncthreads();
    }

    const int wRow = rowBase + wid * 32;
#pragma unroll
    for (int mt = 0; mt < 2; ++mt) {
#pragma unroll
        for (int r = 0; r < 4; ++r) {
            const int R = wRow + mt * 16 + quad * 4 + r;
            if (F32OUT) {
                float* crow = C32 + (size_t)R * N + colBase;
#pragma unroll
                for (int ct = 0; ct < 4; ++ct)
                    crow[ct * 16 + l16] = acc[mt][ct][r];
            } else if (ROPE) {
                u16* crow = C16 + (size_t)R * N + colBase;
                const int s = R & (SEQ - 1);
#pragma unroll
                for (int ct = 0; ct < 2; ++ct) {
                    const int dl = ct * 16 + l16;           // 0..31
                    float lo = acc[mt][ct][r];
                    float hi = acc[mt][ct + 2][r];
                    float cs = cosT[s * 32 + dl];
                    float sn = sinT[s * 32 + dl];
                    crow[dl]      = f2b((lo * cs - hi * sn) * scale);
                    crow[dl + 32] = f2b((hi * cs + lo * sn) * scale);
                }
            } else {
                u16* crow = C16 + (size_t)R * N + colBase;
#pragma unroll
                for (int ct = 0; ct < 4; ++ct)
                    crow[ct * 16 + l16] = f2b(acc[mt][ct][r]);
            }
        }
    }
}

// ------------------------------------------------------- flash attention
// Block = 256 thr = 4 waves; one (b, h, 128-row q-tile) per block.
// Wave w owns q-rows [qt*128 + 32w, +32). K-tiles of 64 keys, online softmax.
// Layouts (mfma_f32_16x16x32_bf16):
//   A[m=l16][k=quad*8+j], B[k=quad*8+j][n=l16], C/D row=quad*4+reg col=l16.
// Ks: [key][dim] with XOR chunk swizzle (chunk_phys = chunk ^ (key&7)).
// Vt: [dim][key] stride 72 for contiguous PV B-frags.
// Ps: per-wave P tile [32][72] for the C-layout -> A-layout round trip.
__global__ __launch_bounds__(256) void flash_attn(
    const u16* __restrict__ Q, const u16* __restrict__ K,
    const u16* __restrict__ V, u16* __restrict__ Y) {
    __shared__ __align__(16) u16 Ks[64 * 64];        // 8 KB
    __shared__ __align__(16) u16 Vt[64 * 72];        // 9 KB
    __shared__ __align__(16) u16 Ps[4 * 32 * 72];    // 18 KB

    const int qt  = 15 - blockIdx.x;     // heavy tiles dispatch first
    const int h   = blockIdx.y;
    const int b   = blockIdx.z;
    const int kvh = h >> 2;
    const int tid  = threadIdx.x;
    const int wid  = tid >> 6;
    const int lane = tid & 63;
    const int quad = lane >> 4;
    const int l16  = lane & 15;

    const int rowBaseW = qt * 128 + wid * 32;         // seq-row base of this wave

    // --- preload Q A-frags (Q already scaled by 1/8 in GEMM epilogue)
    short8 qf[2][2];
#pragma unroll
    for (int mt = 0; mt < 2; ++mt)
#pragma unroll
        for (int ks = 0; ks < 2; ++ks)
            qf[mt][ks] = *(const short8*)&Q[
                (size_t)(b * SEQ + rowBaseW + mt * 16 + l16) * (NHEADS * HD)
                + h * HD + ks * 32 + quad * 8];

    f32x4 o[2][4] = {};
    float mi[2][4], li[2][4];
#pragma unroll
    for (int mt = 0; mt < 2; ++mt)
#pragma unroll
        for (int r = 0; r < 4; ++r) { mi[mt][r] = -3e38f; li[mt][r] = 0.f; }

    const u16* Kg = K + (size_t)b * SEQ * (NKV * HD) + kvh * HD;
    const u16* Vg = V + (size_t)b * SEQ * (NKV * HD) + kvh * HD;
    u16* Psw = Ps + wid * 32 * 72;

    const int nTiles = 2 * qt + 2;
    for (int t = 0; t < nTiles; ++t) {
        const int j0 = t * 64;
        __syncthreads();   // previous tile's K/V reads done

        // --- stage K tile, XOR-swizzled chunks
#pragma unroll
        for (int i = 0; i < 2; ++i) {
            int c   = i * 256 + tid;       // 0..511 16B-chunks
            int key = c >> 3, cc = c & 7;
            short8 val = *(const short8*)&Kg[(size_t)(j0 + key) * (NKV * HD) + cc * 8];
            *(short8*)&Ks[key * 64 + ((cc ^ (key & 7)) * 8)] = val;
        }
        // --- stage V transposed: Vt[dim][key]
        {
            int key = tid & 63, d0 = (tid >> 6) * 16;
            const u16* src = &Vg[(size_t)(j0 + key) * (NKV * HD) + d0];
            short8 va = *(const short8*)src;
            short8 vb = *(const short8*)(src + 8);
#pragma unroll
            for (int i = 0; i < 8; ++i) Vt[(d0 + i) * 72 + key] = (u16)va[i];
#pragma unroll
            for (int i = 0; i < 8; ++i) Vt[(d0 + 8 + i) * 72 + key] = (u16)vb[i];
        }
        __syncthreads();

        // --- S = Q @ K^T  (16 MFMA)
        f32x4 s[2][4] = {};
#pragma unroll
        for (int ks = 0; ks < 2; ++ks)
#pragma unroll
            for (int ct = 0; ct < 4; ++ct) {
                int key = ct * 16 + l16;
                int cc  = (ks * 4 + quad) ^ (key & 7);
                short8 bk = *(const short8*)&Ks[key * 64 + cc * 8];
#pragma unroll
                for (int mt = 0; mt < 2; ++mt)
                    s[mt][ct] = __builtin_amdgcn_mfma_f32_16x16x32_bf16(
                        qf[mt][ks], bk, s[mt][ct], 0, 0, 0);
            }

        // --- causal mask. Gate vs wave MIN row (rowBaseW): round-4 bug was
        // comparing vs max row (rowBaseW+31), which skipped the diagonal tile
        // for odd-wid waves (j0+63 == rowBaseW+31 fails strict >).
        if (j0 + 63 > rowBaseW) {
#pragma unroll
            for (int mt = 0; mt < 2; ++mt)
#pragma unroll
                for (int ct = 0; ct < 4; ++ct)
#pragma unroll
                    for (int r = 0; r < 4; ++r) {
                        int R = rowBaseW + mt * 16 + quad * 4 + r;
                        int J = j0 + ct * 16 + l16;
                        if (J > R) s[mt][ct][r] = -3e38f;
                    }
        }

        // --- online softmax
#pragma unroll
        for (int mt = 0; mt < 2; ++mt)
#pragma unroll
            for (int r = 0; r < 4; ++r) {
                float rmax = fmaxf(fmaxf(s[mt][0][r], s[mt][1][r]),
                                   fmaxf(s[mt][2][r], s[mt][3][r]));
                rmax = fmaxf(rmax, __shfl_xor(rmax, 1, 64));
                rmax = fmaxf(rmax, __shfl_xor(rmax, 2, 64));
                rmax = fmaxf(rmax, __shfl_xor(rmax, 4, 64));
                rmax = fmaxf(rmax, __shfl_xor(rmax, 8, 64));
                float mnew  = fmaxf(mi[mt][r], rmax);
                float alpha = __expf(mi[mt][r] - mnew);
                mi[mt][r] = mnew;
                float rs = 0.f;
#pragma unroll
                for (int ct = 0; ct < 4; ++ct) {
                    float p = __expf(s[mt][ct][r] - mnew);
                    s[mt][ct][r] = p;
                    rs += p;
                    o[mt][ct][r] *= alpha;
                }
                rs += __shfl_xor(rs, 1, 64);
                rs += __shfl_xor(rs, 2, 64);
                rs += __shfl_xor(rs, 4, 64);
                rs += __shfl_xor(rs, 8, 64);
                li[mt][r] = li[mt][r] * alpha + rs;
            }

        // --- P: C-layout -> LDS -> A-layout (wave-private, no barrier)
#pragma unroll
        for (int mt = 0; mt < 2; ++mt)
#pragma unroll
            for (int ct = 0; ct < 4; ++ct)
#pragma unroll
                for (int r = 0; r < 4; ++r)
                    Psw[(mt * 16 + quad * 4 + r) * 72 + ct * 16 + l16] =
                        f2b(s[mt][ct][r]);

        // --- O += P @ V  (16 MFMA)
        short8 pa[2][2];
#pragma unroll
        for (int mt = 0; mt < 2; ++mt)
#pragma unroll
            for (int ks = 0; ks < 2; ++ks)
                pa[mt][ks] = *(const short8*)&Psw[(mt * 16 + l16) * 72 + ks * 32 + quad * 8];
#pragma unroll
        for (int ks = 0; ks < 2; ++ks)
#pragma unroll
            for (int ct = 0; ct < 4; ++ct) {
                short8 vbf = *(const short8*)&Vt[(ct * 16 + l16) * 72 + ks * 32 + quad * 8];
#pragma unroll
                for (int mt = 0; mt < 2; ++mt)
                    o[mt][ct] = __builtin_amdgcn_mfma_f32_16x16x32_bf16(
                        pa[mt][ks], vbf, o[mt][ct], 0, 0, 0);
            }
    }

    // --- normalize + store
#pragma unroll
    for (int mt = 0; mt < 2; ++mt) {
        float rli[4];
#pragma unroll
        for (int r = 0; r < 4; ++r) rli[r] = 1.0f / li[mt][r];
#pragma unroll
        for (int r = 0; r < 4; ++r) {
            int R = rowBaseW + mt * 16 + quad * 4 + r;
            u16* yrow = Y + (size_t)(b * SEQ + R) * (NHEADS * HD) + h * HD;
#pragma unroll
            for (int ct = 0; ct < 4; ++ct)
                yrow[ct * 16 + l16] = f2b(o[mt][ct][r] * rli[r]);
        }
    }
}

// ---------------------------------------------------------------- launch
extern "C" void kernel_launch(void* const* d_in, const int* in_sizes, int n_in,
                              void* d_out, int out_size, void* d_ws, size_t ws_size,
                              hipStream_t stream) {
    const float* x  = (const float*)d_in[0];
    const float* Wq = (const float*)d_in[1];
    const float* Wk = (const float*)d_in[2];
    const float* Wv = (const float*)d_in[3];
    const float* Wo = (const float*)d_in[4];
    float* out = (float*)d_out;   // f32 output

    char* ws = (char*)d_ws;
    u16*  xb   = (u16*)(ws);                     // 16 MB  4096x2048 bf16
    u16*  WqT  = (u16*)(ws + 16777216);          //  8 MB
    u16*  WkT  = (u16*)(ws + 25165824);          //  2 MB
    u16*  WvT  = (u16*)(ws + 27262976);          //  2 MB
    u16*  WoT  = (u16*)(ws + 29360128);          //  8 MB
    u16*  Qb   = (u16*)(ws + 37748736);          // 16 MB (roped, pre-scaled 1/8)
    u16*  Kb   = (u16*)(ws + 54525952);          //  4 MB (roped)
    u16*  Vb   = (u16*)(ws + 58720256);          //  4 MB
    u16*  Yb   = (u16*)(ws + 62914560);          // 16 MB
    float* cosT = (float*)(ws + 79691776);       // 256 KB
    float* sinT = (float*)(ws + 79953920);       // 256 KB

    rope_table_kernel<<<dim3(65536 / 256), 256, 0, stream>>>(cosT, sinT);

    cvt_f32_bf16<<<dim3(MROWS * DM / 4 / 256), 256, 0, stream>>>(x, xb, MROWS * DM / 4);

    dim3 tb(32, 8);
    transpose_f32_bf16<<<dim3(2048/32, 2048/32), tb, 0, stream>>>(Wq, WqT, 2048, 2048);
    transpose_f32_bf16<<<dim3( 512/32, 2048/32), tb, 0, stream>>>(Wk, WkT, 2048,  512);
    transpose_f32_bf16<<<dim3( 512/32, 2048/32), tb, 0, stream>>>(Wv, WvT, 2048,  512);
    transpose_f32_bf16<<<dim3(2048/32, 2048/32), tb, 0, stream>>>(Wo, WoT, 2048, 2048);

    gemm_bt<1,0><<<dim3(2048/64, MROWS/128), 256, 0, stream>>>(xb, WqT, Qb, nullptr, MROWS, 2048, 2048, cosT, sinT, 0.125f);
    gemm_bt<1,0><<<dim3( 512/64, MROWS/128), 256, 0, stream>>>(xb, WkT, Kb, nullptr, MROWS,  512, 2048, cosT, sinT, 1.0f);
    gemm_bt<0,0><<<dim3( 512/64, MROWS/128), 256, 0, stream>>>(xb, WvT, Vb, nullptr, MROWS,  512, 2048, nullptr, nullptr, 1.0f);

    flash_attn<<<dim3(16, NHEADS, 2), 256, 0, stream>>>(Qb, Kb, Vb, Yb);

    gemm_bt<0,1><<<dim3(2048/64, MROWS/128), 256, 0, stream>>>(Yb, WoT, nullptr, out, MROWS, 2048, 2048, nullptr, nullptr, 1.0f);
}

// Round 6
// 425.698 us; speedup vs baseline: 9.6671x; 1.3804x over previous
//
#include <hip/hip_runtime.h>
#include <cstdint>

typedef unsigned short u16;
typedef __attribute__((ext_vector_type(8))) short short8;   // bf16x8 MFMA frag
typedef __attribute__((ext_vector_type(4))) float f32x4;    // fp32x4 accumulator

#define SEQ     2048
#define NHEADS  32
#define NKV     8
#define HD      64
#define DM      2048
#define MROWS   4096   // BATCH * SEQ
#define KVSTR   1024   // fused KV row stride (8 K-heads | 8 V-heads)

__device__ __forceinline__ float b2f(unsigned int u) {
    return __builtin_bit_cast(float, u << 16);
}
__device__ __forceinline__ u16 f2b(float f) {
    unsigned int u = __builtin_bit_cast(unsigned int, f);
    return (u16)((u + 0x7fffu + ((u >> 16) & 1u)) >> 16);   // RNE
}

// async global->LDS, 16B per lane; LDS dest = wave-uniform base + lane*16
#define GLOAD_LDS16(g, l)                                              \
    __builtin_amdgcn_global_load_lds(                                  \
        (const __attribute__((address_space(1))) void*)(g),            \
        (__attribute__((address_space(3))) void*)(l), 16, 0, 0)

// ------------------------------------------------------------- f32 -> bf16
__global__ __launch_bounds__(256) void cvt_f32_bf16(
    const float* __restrict__ in, u16* __restrict__ out, int n4) {
    int i = blockIdx.x * 256 + threadIdx.x;
    if (i < n4) {
        float4 v = ((const float4*)in)[i];
        ushort4 o;
        o.x = f2b(v.x); o.y = f2b(v.y); o.z = f2b(v.z); o.w = f2b(v.w);
        ((ushort4*)out)[i] = o;
    }
}

// ------------------------------------------------------------- RoPE tables
__global__ __launch_bounds__(256) void rope_table_kernel(
    float* __restrict__ cosT, float* __restrict__ sinT) {
    int idx = blockIdx.x * 256 + threadIdx.x;     // 65536 = 2048*32
    int s  = idx >> 5;
    int dl = idx & 31;
    float inv_freq = exp2f((float)dl * -0.41524101186092025f); // 10000^(-dl/32)
    float ang = (float)s * inv_freq;
    float sn, cs;
    sincosf(ang, &sn, &cs);                        // accurate (range-reduced)
    cosT[idx] = cs;
    sinT[idx] = sn;
}

// ------------------------------------------------- transpose + downcast
__global__ __launch_bounds__(256) void transpose_f32_bf16(
    const float* __restrict__ in, u16* __restrict__ out, int K, int N) {
    __shared__ float tile[32][33];
    int n0 = blockIdx.x * 32, k0 = blockIdx.y * 32;
    int tx = threadIdx.x, ty = threadIdx.y;   // 32 x 8
    for (int r = ty; r < 32; r += 8)
        tile[r][tx] = in[(size_t)(k0 + r) * N + n0 + tx];
    __syncthreads();
    for (int r = ty; r < 32; r += 8)
        out[(size_t)(n0 + r) * K + k0 + tx] = f2b(tile[tx][r]);
}

// ------------------------------------------------------- GEMM (m97-style)
// C[M x N] = A[M x K] @ B, BT = B^T (N x K row-major). 128x128 block tile,
// 4 waves in 2x2 (64x64 each, acc 4x4), BK=32, unpadded LDS, async
// global_load_lds width=16 staging (lane-contiguous row-major layout).
// RMODE: 0 none; 1 rope whole tile (Q, fold `scale`); 2 rope iff col<512 (KV).
// F32OUT: write f32 C (final projection).
template <int RMODE, int F32OUT>
__global__ __launch_bounds__(256) void gemm_bt128(
    const u16* __restrict__ A, const u16* __restrict__ BT,
    u16* __restrict__ C16, float* __restrict__ C32,
    int M, int N, int K,
    const float* __restrict__ cosT, const float* __restrict__ sinT,
    float scale) {
    constexpr int BK = 32;
    __shared__ __align__(16) u16 As[128 * BK];   // 8 KB
    __shared__ __align__(16) u16 Bs[128 * BK];   // 8 KB

    const int tid  = threadIdx.x;
    const int wid  = tid >> 6;
    const int lane = tid & 63;
    const int quad = lane >> 4;
    const int l16  = lane & 15;
    const int rowBase = blockIdx.y * 128;
    const int colBase = blockIdx.x * 128;

    const int wr = (wid >> 1) * 64;   // wave row offset in tile
    const int wc = (wid & 1) * 64;    // wave col offset

    // staging: wave w stages rows [32w, 32w+32) of As and Bs, 2 instrs each
    // lane i covers row 32w + j*16 + (i>>2), bytes (i&3)*16 of the 64B row
    const int srow = wid * 32 + (lane >> 2);
    const int scol = (lane & 3) * 8;
    const u16* gA = A  + (size_t)(rowBase + srow) * K + scol;
    const u16* gB = BT + (size_t)(colBase + srow) * K + scol;
    u16* lA0 = &As[(wid * 32) * BK];
    u16* lA1 = &As[(wid * 32 + 16) * BK];
    u16* lB0 = &Bs[(wid * 32) * BK];
    u16* lB1 = &Bs[(wid * 32 + 16) * BK];
    const size_t row16 = (size_t)16 * K;

    f32x4 acc[4][4] = {};

    for (int k0 = 0; k0 < K; k0 += BK) {
        GLOAD_LDS16(gA + k0,         lA0);
        GLOAD_LDS16(gA + k0 + row16, lA1);
        GLOAD_LDS16(gB + k0,         lB0);
        GLOAD_LDS16(gB + k0 + row16, lB1);
        __syncthreads();

        short8 a[4], b[4];
#pragma unroll
        for (int mi = 0; mi < 4; ++mi)
            a[mi] = *(const short8*)&As[(wr + mi * 16 + l16) * BK + quad * 8];
#pragma unroll
        for (int ni = 0; ni < 4; ++ni)
            b[ni] = *(const short8*)&Bs[(wc + ni * 16 + l16) * BK + quad * 8];
#pragma unroll
        for (int mi = 0; mi < 4; ++mi)
#pragma unroll
            for (int ni = 0; ni < 4; ++ni)
                acc[mi][ni] = __builtin_amdgcn_mfma_f32_16x16x32_bf16(
                    a[mi], b[ni], acc[mi][ni], 0, 0, 0);
        __syncthreads();
    }

    const int wRow = rowBase + wr;
    const int wCol = colBase + wc;
    const bool doRope = (RMODE == 1) || (RMODE == 2 && wCol < 512);
#pragma unroll
    for (int mi = 0; mi < 4; ++mi) {
#pragma unroll
        for (int r = 0; r < 4; ++r) {
            const int R = wRow + mi * 16 + quad * 4 + r;
            if (F32OUT) {
                float* crow = C32 + (size_t)R * N + wCol;
#pragma unroll
                for (int ni = 0; ni < 4; ++ni)
                    crow[ni * 16 + l16] = acc[mi][ni][r];
            } else if (doRope) {
                u16* crow = C16 + (size_t)R * N + wCol;
                const int s = R & (SEQ - 1);
#pragma unroll
                for (int ni = 0; ni < 2; ++ni) {
                    const int dl = ni * 16 + l16;           // 0..31
                    float lo = acc[mi][ni][r];
                    float hi = acc[mi][ni + 2][r];
                    float cs = cosT[s * 32 + dl];
                    float sn = sinT[s * 32 + dl];
                    crow[dl]      = f2b((lo * cs - hi * sn) * scale);
                    crow[dl + 32] = f2b((hi * cs + lo * sn) * scale);
                }
            } else {
                u16* crow = C16 + (size_t)R * N + wCol;
#pragma unroll
                for (int ni = 0; ni < 4; ++ni)
                    crow[ni * 16 + l16] = f2b(acc[mi][ni][r]);
            }
        }
    }
}

// ------------------------------------------------------- flash attention
// Triangle pairing: block handles q-tiles {bx, 15-bx} -> 36 key-tiles of
// work per block, uniform. Grid (8, 32, 2) = 512 blocks, 2/CU resident.
// Wave w owns q-rows [qt*128 + 32w, +32). Layouts per mfma_f32_16x16x32_bf16.
__global__ __launch_bounds__(256) void flash_attn(
    const u16* __restrict__ Q, const u16* __restrict__ KV,
    u16* __restrict__ Y) {
    __shared__ __align__(16) u16 Ks[64 * 64];        // 8 KB
    __shared__ __align__(16) u16 Vt[64 * 72];        // 9 KB
    __shared__ __align__(16) u16 Ps[4 * 32 * 72];    // 18 KB

    const int h   = blockIdx.y;
    const int b   = blockIdx.z;
    const int kvh = h >> 2;
    const int tid  = threadIdx.x;
    const int wid  = tid >> 6;
    const int lane = tid & 63;
    const int quad = lane >> 4;
    const int l16  = lane & 15;

    const u16* Kg = KV + (size_t)b * SEQ * KVSTR + kvh * HD;
    const u16* Vg = Kg + 512;
    u16* Psw = Ps + wid * 32 * 72;

    for (int half = 0; half < 2; ++half) {
        const int qt = half ? (15 - blockIdx.x) : blockIdx.x;
        const int rowBaseW = qt * 128 + wid * 32;

        // --- preload Q A-frags (Q pre-scaled by 1/8 in GEMM epilogue)
        short8 qf[2][2];
#pragma unroll
        for (int mt = 0; mt < 2; ++mt)
#pragma unroll
            for (int ks = 0; ks < 2; ++ks)
                qf[mt][ks] = *(const short8*)&Q[
                    (size_t)(b * SEQ + rowBaseW + mt * 16 + l16) * (NHEADS * HD)
                    + h * HD + ks * 32 + quad * 8];

        f32x4 o[2][4] = {};
        float mi[2][4], li[2][4];
#pragma unroll
        for (int mt = 0; mt < 2; ++mt)
#pragma unroll
            for (int r = 0; r < 4; ++r) { mi[mt][r] = -3e38f; li[mt][r] = 0.f; }

        const int nTiles = 2 * qt + 2;
        for (int t = 0; t < nTiles; ++t) {
            const int j0 = t * 64;
            __syncthreads();   // previous tile's (or half's) K/V reads done

            // --- stage K tile, XOR-swizzled 16B chunks
#pragma unroll
            for (int i = 0; i < 2; ++i) {
                int c   = i * 256 + tid;       // 0..511
                int key = c >> 3, cc = c & 7;
                short8 val = *(const short8*)&Kg[(size_t)(j0 + key) * KVSTR + cc * 8];
                *(short8*)&Ks[key * 64 + ((cc ^ (key & 7)) * 8)] = val;
            }
            // --- stage V transposed: Vt[dim][key]
            {
                int key = tid & 63, d0 = (tid >> 6) * 16;
                const u16* src = &Vg[(size_t)(j0 + key) * KVSTR + d0];
                short8 va = *(const short8*)src;
                short8 vb = *(const short8*)(src + 8);
#pragma unroll
                for (int i = 0; i < 8; ++i) Vt[(d0 + i) * 72 + key] = (u16)va[i];
#pragma unroll
                for (int i = 0; i < 8; ++i) Vt[(d0 + 8 + i) * 72 + key] = (u16)vb[i];
            }
            __syncthreads();

            // --- S = Q @ K^T  (16 MFMA)
            f32x4 s[2][4] = {};
#pragma unroll
            for (int ks = 0; ks < 2; ++ks)
#pragma unroll
                for (int ct = 0; ct < 4; ++ct) {
                    int key = ct * 16 + l16;
                    int cc  = (ks * 4 + quad) ^ (key & 7);
                    short8 bk = *(const short8*)&Ks[key * 64 + cc * 8];
#pragma unroll
                    for (int mt = 0; mt < 2; ++mt)
                        s[mt][ct] = __builtin_amdgcn_mfma_f32_16x16x32_bf16(
                            qf[mt][ks], bk, s[mt][ct], 0, 0, 0);
                }

            // --- causal mask (gate vs wave MIN row — round-4 lesson)
            if (j0 + 63 > rowBaseW) {
#pragma unroll
                for (int mt = 0; mt < 2; ++mt)
#pragma unroll
                    for (int ct = 0; ct < 4; ++ct)
#pragma unroll
                        for (int r = 0; r < 4; ++r) {
                            int R = rowBaseW + mt * 16 + quad * 4 + r;
                            int J = j0 + ct * 16 + l16;
                            if (J > R) s[mt][ct][r] = -3e38f;
                        }
            }

            // --- online softmax
#pragma unroll
            for (int mt = 0; mt < 2; ++mt)
#pragma unroll
                for (int r = 0; r < 4; ++r) {
                    float rmax = fmaxf(fmaxf(s[mt][0][r], s[mt][1][r]),
                                       fmaxf(s[mt][2][r], s[mt][3][r]));
                    rmax = fmaxf(rmax, __shfl_xor(rmax, 1, 64));
                    rmax = fmaxf(rmax, __shfl_xor(rmax, 2, 64));
                    rmax = fmaxf(rmax, __shfl_xor(rmax, 4, 64));
                    rmax = fmaxf(rmax, __shfl_xor(rmax, 8, 64));
                    float mnew  = fmaxf(mi[mt][r], rmax);
                    float alpha = __expf(mi[mt][r] - mnew);
                    mi[mt][r] = mnew;
                    float rs = 0.f;
#pragma unroll
                    for (int ct = 0; ct < 4; ++ct) {
                        float p = __expf(s[mt][ct][r] - mnew);
                        s[mt][ct][r] = p;
                        rs += p;
                        o[mt][ct][r] *= alpha;
                    }
                    rs += __shfl_xor(rs, 1, 64);
                    rs += __shfl_xor(rs, 2, 64);
                    rs += __shfl_xor(rs, 4, 64);
                    rs += __shfl_xor(rs, 8, 64);
                    li[mt][r] = li[mt][r] * alpha + rs;
                }

            // --- P: C-layout -> LDS -> A-layout (wave-private)
#pragma unroll
            for (int mt = 0; mt < 2; ++mt)
#pragma unroll
                for (int ct = 0; ct < 4; ++ct)
#pragma unroll
                    for (int r = 0; r < 4; ++r)
                        Psw[(mt * 16 + quad * 4 + r) * 72 + ct * 16 + l16] =
                            f2b(s[mt][ct][r]);

            // --- O += P @ V  (16 MFMA)
            short8 pa[2][2];
#pragma unroll
            for (int mt = 0; mt < 2; ++mt)
#pragma unroll
                for (int ks = 0; ks < 2; ++ks)
                    pa[mt][ks] = *(const short8*)&Psw[(mt * 16 + l16) * 72 + ks * 32 + quad * 8];
#pragma unroll
            for (int ks = 0; ks < 2; ++ks)
#pragma unroll
                for (int ct = 0; ct < 4; ++ct) {
                    short8 vbf = *(const short8*)&Vt[(ct * 16 + l16) * 72 + ks * 32 + quad * 8];
#pragma unroll
                    for (int mt = 0; mt < 2; ++mt)
                        o[mt][ct] = __builtin_amdgcn_mfma_f32_16x16x32_bf16(
                            pa[mt][ks], vbf, o[mt][ct], 0, 0, 0);
                }
        }

        // --- normalize + store this half's q-tile
#pragma unroll
        for (int mt = 0; mt < 2; ++mt) {
            float rli[4];
#pragma unroll
            for (int r = 0; r < 4; ++r) rli[r] = 1.0f / li[mt][r];
#pragma unroll
            for (int r = 0; r < 4; ++r) {
                int R = rowBaseW + mt * 16 + quad * 4 + r;
                u16* yrow = Y + (size_t)(b * SEQ + R) * (NHEADS * HD) + h * HD;
#pragma unroll
                for (int ct = 0; ct < 4; ++ct)
                    yrow[ct * 16 + l16] = f2b(o[mt][ct][r] * rli[r]);
            }
        }
    }
}

// ---------------------------------------------------------------- launch
extern "C" void kernel_launch(void* const* d_in, const int* in_sizes, int n_in,
                              void* d_out, int out_size, void* d_ws, size_t ws_size,
                              hipStream_t stream) {
    const float* x  = (const float*)d_in[0];
    const float* Wq = (const float*)d_in[1];
    const float* Wk = (const float*)d_in[2];
    const float* Wv = (const float*)d_in[3];
    const float* Wo = (const float*)d_in[4];
    float* out = (float*)d_out;   // f32 output

    char* ws = (char*)d_ws;
    u16*  xb    = (u16*)(ws);                    // 16 MB  4096x2048 bf16
    u16*  WqT   = (u16*)(ws + 16777216);         //  8 MB  2048x2048
    u16*  WkvT  = (u16*)(ws + 25165824);         //  4 MB  1024x2048 (Wk^T | Wv^T)
    u16*  WoT   = (u16*)(ws + 29360128);         //  8 MB  2048x2048
    u16*  Qb    = (u16*)(ws + 37748736);         // 16 MB  (roped, pre-scaled 1/8)
    u16*  KVb   = (u16*)(ws + 54525952);         //  8 MB  4096x1024 (K roped | V)
    u16*  Yb    = (u16*)(ws + 62914560);         // 16 MB
    float* cosT = (float*)(ws + 79691776);       // 256 KB
    float* sinT = (float*)(ws + 79953920);       // 256 KB

    rope_table_kernel<<<dim3(65536 / 256), 256, 0, stream>>>(cosT, sinT);

    cvt_f32_bf16<<<dim3(MROWS * DM / 4 / 256), 256, 0, stream>>>(x, xb, MROWS * DM / 4);

    dim3 tb(32, 8);
    transpose_f32_bf16<<<dim3(2048/32, 2048/32), tb, 0, stream>>>(Wq, WqT, 2048, 2048);
    transpose_f32_bf16<<<dim3( 512/32, 2048/32), tb, 0, stream>>>(Wk, WkvT, 2048, 512);
    transpose_f32_bf16<<<dim3( 512/32, 2048/32), tb, 0, stream>>>(Wv, WkvT + 512 * 2048, 2048, 512);
    transpose_f32_bf16<<<dim3(2048/32, 2048/32), tb, 0, stream>>>(Wo, WoT, 2048, 2048);

    gemm_bt128<1,0><<<dim3(16, 32), 256, 0, stream>>>(xb, WqT,  Qb,  nullptr, MROWS, 2048, 2048, cosT, sinT, 0.125f);
    gemm_bt128<2,0><<<dim3( 8, 32), 256, 0, stream>>>(xb, WkvT, KVb, nullptr, MROWS, 1024, 2048, cosT, sinT, 1.0f);

    flash_attn<<<dim3(8, NHEADS, 2), 256, 0, stream>>>(Qb, KVb, Yb);

    gemm_bt128<0,1><<<dim3(16, 32), 256, 0, stream>>>(Yb, WoT, nullptr, out, MROWS, 2048, 2048, nullptr, nullptr, 1.0f);
}

// Round 7
// 400.708 us; speedup vs baseline: 10.2700x; 1.0624x over previous
//
#include <hip/hip_runtime.h>
#include <cstdint>

typedef unsigned short u16;
typedef __attribute__((ext_vector_type(8))) short short8;   // bf16x8 MFMA frag
typedef __attribute__((ext_vector_type(4))) float f32x4;    // fp32x4 accumulator

#define SEQ     2048
#define NHEADS  32
#define NKV     8
#define HD      64
#define DM      2048
#define MROWS   4096   // BATCH * SEQ
#define KVSTR   1024   // fused KV row stride (8 K-heads | 8 V-heads)
#define PSTR    88     // Ps row stride (u16): 176B, 16B-aligned, 2-way banks

__device__ __forceinline__ float b2f(unsigned int u) {
    return __builtin_bit_cast(float, u << 16);
}
__device__ __forceinline__ u16 f2b(float f) {
    unsigned int u = __builtin_bit_cast(unsigned int, f);
    return (u16)((u + 0x7fffu + ((u >> 16) & 1u)) >> 16);   // RNE
}

// async global->LDS, 16B per lane; LDS dest = wave-uniform base + lane*16
#define GLOAD_LDS16(g, l)                                              \
    __builtin_amdgcn_global_load_lds(                                  \
        (const __attribute__((address_space(1))) void*)(g),            \
        (__attribute__((address_space(3))) void*)(l), 16, 0, 0)

// ------------------------------------------------------------- f32 -> bf16
__global__ __launch_bounds__(256) void cvt_f32_bf16(
    const float* __restrict__ in, u16* __restrict__ out, int n4) {
    int i = blockIdx.x * 256 + threadIdx.x;
    if (i < n4) {
        float4 v = ((const float4*)in)[i];
        ushort4 o;
        o.x = f2b(v.x); o.y = f2b(v.y); o.z = f2b(v.z); o.w = f2b(v.w);
        ((ushort4*)out)[i] = o;
    }
}

// ------------------------------------------------------------- RoPE tables
__global__ __launch_bounds__(256) void rope_table_kernel(
    float* __restrict__ cosT, float* __restrict__ sinT) {
    int idx = blockIdx.x * 256 + threadIdx.x;     // 65536 = 2048*32
    int s  = idx >> 5;
    int dl = idx & 31;
    float inv_freq = exp2f((float)dl * -0.41524101186092025f); // 10000^(-dl/32)
    float ang = (float)s * inv_freq;
    float sn, cs;
    sincosf(ang, &sn, &cs);                        // accurate (range-reduced)
    cosT[idx] = cs;
    sinT[idx] = sn;
}

// ------------------------------------------------- transpose + downcast
__global__ __launch_bounds__(256) void transpose_f32_bf16(
    const float* __restrict__ in, u16* __restrict__ out, int K, int N) {
    __shared__ float tile[32][33];
    int n0 = blockIdx.x * 32, k0 = blockIdx.y * 32;
    int tx = threadIdx.x, ty = threadIdx.y;   // 32 x 8
    for (int r = ty; r < 32; r += 8)
        tile[r][tx] = in[(size_t)(k0 + r) * N + n0 + tx];
    __syncthreads();
    for (int r = ty; r < 32; r += 8)
        out[(size_t)(n0 + r) * K + k0 + tx] = f2b(tile[tx][r]);
}

// ------------------------------------------------------- GEMM core macro
// 128x128 block tile, 4 waves 2x2 (64x64 each, acc 4x4), BK=32, unpadded
// LDS, global_load_lds width=16 (m97 structure).
#define GEMM_BODY(A, BT, Kdim)                                             \
    constexpr int BK = 32;                                                 \
    __shared__ __align__(16) u16 As[128 * BK];                             \
    __shared__ __align__(16) u16 Bs[128 * BK];                             \
    const int tid  = threadIdx.x;                                          \
    const int wid  = tid >> 6;                                             \
    const int lane = tid & 63;                                             \
    const int quad = lane >> 4;                                            \
    const int l16  = lane & 15;                                            \
    const int rowBase = blockIdx.y * 128;                                  \
    const int colBase = blockIdx.x * 128;                                  \
    const int wr = (wid >> 1) * 64;                                        \
    const int wc = (wid & 1) * 64;                                         \
    const int srow = wid * 32 + (lane >> 2);                               \
    const int scol = (lane & 3) * 8;                                       \
    const u16* gA = (A)  + (size_t)(rowBase + srow) * (Kdim) + scol;       \
    const u16* gB = (BT) + (size_t)(colBase + srow) * (Kdim) + scol;       \
    u16* lA0 = &As[(wid * 32) * BK];                                       \
    u16* lA1 = &As[(wid * 32 + 16) * BK];                                  \
    u16* lB0 = &Bs[(wid * 32) * BK];                                       \
    u16* lB1 = &Bs[(wid * 32 + 16) * BK];                                  \
    const size_t row16 = (size_t)16 * (Kdim);                              \
    f32x4 acc[4][4] = {};                                                  \
    for (int k0 = 0; k0 < (Kdim); k0 += BK) {                              \
        GLOAD_LDS16(gA + k0,         lA0);                                 \
        GLOAD_LDS16(gA + k0 + row16, lA1);                                 \
        GLOAD_LDS16(gB + k0,         lB0);                                 \
        GLOAD_LDS16(gB + k0 + row16, lB1);                                 \
        __syncthreads();                                                   \
        short8 a[4], b[4];                                                 \
        _Pragma("unroll")                                                  \
        for (int mi = 0; mi < 4; ++mi)                                     \
            a[mi] = *(const short8*)&As[(wr + mi * 16 + l16) * BK + quad * 8]; \
        _Pragma("unroll")                                                  \
        for (int ni = 0; ni < 4; ++ni)                                     \
            b[ni] = *(const short8*)&Bs[(wc + ni * 16 + l16) * BK + quad * 8]; \
        _Pragma("unroll")                                                  \
        for (int mi = 0; mi < 4; ++mi)                                     \
            _Pragma("unroll")                                              \
            for (int ni = 0; ni < 4; ++ni)                                 \
                acc[mi][ni] = __builtin_amdgcn_mfma_f32_16x16x32_bf16(     \
                    a[mi], b[ni], acc[mi][ni], 0, 0, 0);                   \
        __syncthreads();                                                   \
    }                                                                      \
    const int wRow = rowBase + wr;                                         \
    const int wCol = colBase + wc;

// ------------------------------------------------------- fused QKV GEMM
// C = x @ [Wq | Wk | Wv] (N=3072). Columns: [0,2048) Q -> rope*1/8 -> Qb;
// [2048,2560) K -> rope -> KVb; [2560,3072) V -> plain -> KVb. All branches
// wave-uniform (wCol is 64-aligned, segments 512-aligned).
__global__ __launch_bounds__(256) void gemm_qkv(
    const u16* __restrict__ A, const u16* __restrict__ BT,
    u16* __restrict__ Qb, u16* __restrict__ KVb,
    const float* __restrict__ cosT, const float* __restrict__ sinT) {
    GEMM_BODY(A, BT, DM)

    u16* dst;
    int dstride, dcol;
    float scale;
    bool doRope;
    if (wCol < 2048)      { dst = Qb;  dstride = 2048; dcol = wCol;        scale = 0.125f; doRope = true;  }
    else if (wCol < 2560) { dst = KVb; dstride = 1024; dcol = wCol - 2048; scale = 1.0f;   doRope = true;  }
    else                  { dst = KVb; dstride = 1024; dcol = wCol - 2048; scale = 1.0f;   doRope = false; }

#pragma unroll
    for (int mi = 0; mi < 4; ++mi) {
#pragma unroll
        for (int r = 0; r < 4; ++r) {
            const int R = wRow + mi * 16 + quad * 4 + r;
            u16* crow = dst + (size_t)R * dstride + dcol;
            if (doRope) {
                const int s = R & (SEQ - 1);
#pragma unroll
                for (int ni = 0; ni < 2; ++ni) {
                    const int dl = ni * 16 + l16;           // 0..31
                    float lo = acc[mi][ni][r];
                    float hi = acc[mi][ni + 2][r];
                    float cs = cosT[s * 32 + dl];
                    float sn = sinT[s * 32 + dl];
                    crow[dl]      = f2b((lo * cs - hi * sn) * scale);
                    crow[dl + 32] = f2b((hi * cs + lo * sn) * scale);
                }
            } else {
#pragma unroll
                for (int ni = 0; ni < 4; ++ni)
                    crow[ni * 16 + l16] = f2b(acc[mi][ni][r]);
            }
        }
    }
}

// ------------------------------------------------------- output GEMM (f32)
__global__ __launch_bounds__(256) void gemm_out(
    const u16* __restrict__ A, const u16* __restrict__ BT,
    float* __restrict__ C32) {
    GEMM_BODY(A, BT, DM)
#pragma unroll
    for (int mi = 0; mi < 4; ++mi) {
#pragma unroll
        for (int r = 0; r < 4; ++r) {
            const int R = wRow + mi * 16 + quad * 4 + r;
            float* crow = C32 + (size_t)R * DM + wCol;
#pragma unroll
            for (int ni = 0; ni < 4; ++ni)
                crow[ni * 16 + l16] = acc[mi][ni][r];
        }
    }
}

// ------------------------------------------------------- flash attention
// Triangle pairing: block handles q-tiles {bx, 15-bx} -> uniform 36 key-tile
// work. Grid (8, 32, 2) = 512 blocks. Wave w owns q-rows [qt*128+32w, +32).
// Software pipeline: K/V globals for tile t+1 prefetched into registers
// right after the stage barrier; compute of tile t overlaps the loads.
__global__ __launch_bounds__(256) void flash_attn(
    const u16* __restrict__ Q, const u16* __restrict__ KV,
    u16* __restrict__ Y) {
    __shared__ __align__(16) u16 Ks[64 * 64];         // 8 KB, XOR-swizzled
    __shared__ __align__(16) u16 Vt[64 * 72];         // 9 KB, [dim][key]
    __shared__ __align__(16) u16 Ps[4 * 32 * PSTR];   // 22 KB

    const int h   = blockIdx.y;
    const int b   = blockIdx.z;
    const int kvh = h >> 2;
    const int tid  = threadIdx.x;
    const int wid  = tid >> 6;
    const int lane = tid & 63;
    const int quad = lane >> 4;
    const int l16  = lane & 15;

    const u16* Kg = KV + (size_t)b * SEQ * KVSTR + kvh * HD;
    const u16* Vg = Kg + 512;
    u16* Psw = Ps + wid * 32 * PSTR;

    // staging coords
    const int kc0 = tid,        kKey0 = kc0 >> 3, kCc0 = kc0 & 7;
    const int kc1 = 256 + tid,  kKey1 = kc1 >> 3, kCc1 = kc1 & 7;
    const int vkp = tid & 31;          // key pair: keys 2vkp, 2vkp+1
    const int vd0 = (tid >> 5) * 8;    // 8 dims

    for (int half = 0; half < 2; ++half) {
        const int qt = half ? (15 - blockIdx.x) : blockIdx.x;
        const int rowBaseW = qt * 128 + wid * 32;

        // --- preload Q A-frags (Q pre-scaled by 1/8 in GEMM epilogue)
        short8 qf[2][2];
#pragma unroll
        for (int mt = 0; mt < 2; ++mt)
#pragma unroll
            for (int ks = 0; ks < 2; ++ks)
                qf[mt][ks] = *(const short8*)&Q[
                    (size_t)(b * SEQ + rowBaseW + mt * 16 + l16) * (NHEADS * HD)
                    + h * HD + ks * 32 + quad * 8];

        f32x4 o[2][4] = {};
        float mi[2][4], li[2][4];
#pragma unroll
        for (int mt = 0; mt < 2; ++mt)
#pragma unroll
            for (int r = 0; r < 4; ++r) { mi[mt][r] = -3e38f; li[mt][r] = 0.f; }

        const int nTiles = 2 * qt + 2;

        // --- prefetch tile 0
        short8 kreg0 = *(const short8*)&Kg[(size_t)kKey0 * KVSTR + kCc0 * 8];
        short8 kreg1 = *(const short8*)&Kg[(size_t)kKey1 * KVSTR + kCc1 * 8];
        short8 vrA   = *(const short8*)&Vg[(size_t)(2 * vkp)     * KVSTR + vd0];
        short8 vrB   = *(const short8*)&Vg[(size_t)(2 * vkp + 1) * KVSTR + vd0];

        for (int t = 0; t < nTiles; ++t) {
            const int j0 = t * 64;
            __syncthreads();   // previous tile's LDS reads done

            // --- write staged K (XOR-swizzled 16B chunks)
            *(short8*)&Ks[kKey0 * 64 + ((kCc0 ^ (kKey0 & 7)) * 8)] = kreg0;
            *(short8*)&Ks[kKey1 * 64 + ((kCc1 ^ (kKey1 & 7)) * 8)] = kreg1;
            // --- write staged V as packed key-pairs (8 x b32, conflict-free)
#pragma unroll
            for (int i = 0; i < 8; ++i) {
                unsigned int w = (unsigned int)(u16)vrA[i]
                               | ((unsigned int)(u16)vrB[i] << 16);
                ((unsigned int*)Vt)[(vd0 + i) * 36 + vkp] = w;
            }
            __syncthreads();

            // --- prefetch tile t+1 (overlaps with compute below)
            if (t + 1 < nTiles) {
                const size_t jn = (size_t)(j0 + 64);
                kreg0 = *(const short8*)&Kg[(jn + kKey0) * KVSTR + kCc0 * 8];
                kreg1 = *(const short8*)&Kg[(jn + kKey1) * KVSTR + kCc1 * 8];
                vrA   = *(const short8*)&Vg[(jn + 2 * vkp)     * KVSTR + vd0];
                vrB   = *(const short8*)&Vg[(jn + 2 * vkp + 1) * KVSTR + vd0];
            }

            // --- S = Q @ K^T  (16 MFMA)
            f32x4 s[2][4] = {};
#pragma unroll
            for (int ks = 0; ks < 2; ++ks)
#pragma unroll
                for (int ct = 0; ct < 4; ++ct) {
                    int key = ct * 16 + l16;
                    int cc  = (ks * 4 + quad) ^ (key & 7);
                    short8 bk = *(const short8*)&Ks[key * 64 + cc * 8];
#pragma unroll
                    for (int mt = 0; mt < 2; ++mt)
                        s[mt][ct] = __builtin_amdgcn_mfma_f32_16x16x32_bf16(
                            qf[mt][ks], bk, s[mt][ct], 0, 0, 0);
                }

            // --- causal mask (gate vs wave MIN row — round-4 lesson)
            if (j0 + 63 > rowBaseW) {
#pragma unroll
                for (int mt = 0; mt < 2; ++mt)
#pragma unroll
                    for (int ct = 0; ct < 4; ++ct)
#pragma unroll
                        for (int r = 0; r < 4; ++r) {
                            int R = rowBaseW + mt * 16 + quad * 4 + r;
                            int J = j0 + ct * 16 + l16;
                            if (J > R) s[mt][ct][r] = -3e38f;
                        }
            }

            // --- online softmax
#pragma unroll
            for (int mt = 0; mt < 2; ++mt)
#pragma unroll
                for (int r = 0; r < 4; ++r) {
                    float rmax = fmaxf(fmaxf(s[mt][0][r], s[mt][1][r]),
                                       fmaxf(s[mt][2][r], s[mt][3][r]));
                    rmax = fmaxf(rmax, __shfl_xor(rmax, 1, 64));
                    rmax = fmaxf(rmax, __shfl_xor(rmax, 2, 64));
                    rmax = fmaxf(rmax, __shfl_xor(rmax, 4, 64));
                    rmax = fmaxf(rmax, __shfl_xor(rmax, 8, 64));
                    float mnew  = fmaxf(mi[mt][r], rmax);
                    float alpha = __expf(mi[mt][r] - mnew);
                    mi[mt][r] = mnew;
                    float rs = 0.f;
#pragma unroll
                    for (int ct = 0; ct < 4; ++ct) {
                        float p = __expf(s[mt][ct][r] - mnew);
                        s[mt][ct][r] = p;
                        rs += p;
                        o[mt][ct][r] *= alpha;
                    }
                    rs += __shfl_xor(rs, 1, 64);
                    rs += __shfl_xor(rs, 2, 64);
                    rs += __shfl_xor(rs, 4, 64);
                    rs += __shfl_xor(rs, 8, 64);
                    li[mt][r] = li[mt][r] * alpha + rs;
                }

            // --- P: C-layout -> LDS -> A-layout (wave-private)
#pragma unroll
            for (int mt = 0; mt < 2; ++mt)
#pragma unroll
                for (int ct = 0; ct < 4; ++ct)
#pragma unroll
                    for (int r = 0; r < 4; ++r)
                        Psw[(mt * 16 + quad * 4 + r) * PSTR + ct * 16 + l16] =
                            f2b(s[mt][ct][r]);

            // --- O += P @ V  (16 MFMA)
            short8 pa[2][2];
#pragma unroll
            for (int mt = 0; mt < 2; ++mt)
#pragma unroll
                for (int ks = 0; ks < 2; ++ks)
                    pa[mt][ks] = *(const short8*)&Psw[(mt * 16 + l16) * PSTR + ks * 32 + quad * 8];
#pragma unroll
            for (int ks = 0; ks < 2; ++ks)
#pragma unroll
                for (int ct = 0; ct < 4; ++ct) {
                    short8 vbf = *(const short8*)&Vt[(ct * 16 + l16) * 72 + ks * 32 + quad * 8];
#pragma unroll
                    for (int mt = 0; mt < 2; ++mt)
                        o[mt][ct] = __builtin_amdgcn_mfma_f32_16x16x32_bf16(
                            pa[mt][ks], vbf, o[mt][ct], 0, 0, 0);
                }
        }

        // --- normalize + store this half's q-tile
#pragma unroll
        for (int mt = 0; mt < 2; ++mt) {
            float rli[4];
#pragma unroll
            for (int r = 0; r < 4; ++r) rli[r] = 1.0f / li[mt][r];
#pragma unroll
            for (int r = 0; r < 4; ++r) {
                int R = rowBaseW + mt * 16 + quad * 4 + r;
                u16* yrow = Y + (size_t)(b * SEQ + R) * (NHEADS * HD) + h * HD;
#pragma unroll
                for (int ct = 0; ct < 4; ++ct)
                    yrow[ct * 16 + l16] = f2b(o[mt][ct][r] * rli[r]);
            }
        }
    }
}

// ---------------------------------------------------------------- launch
extern "C" void kernel_launch(void* const* d_in, const int* in_sizes, int n_in,
                              void* d_out, int out_size, void* d_ws, size_t ws_size,
                              hipStream_t stream) {
    const float* x  = (const float*)d_in[0];
    const float* Wq = (const float*)d_in[1];
    const float* Wk = (const float*)d_in[2];
    const float* Wv = (const float*)d_in[3];
    const float* Wo = (const float*)d_in[4];
    float* out = (float*)d_out;   // f32 output

    char* ws = (char*)d_ws;
    u16*  xb    = (u16*)(ws);                    // 16 MB  4096x2048 bf16
    u16*  WqkvT = (u16*)(ws + 16777216);         // 12 MB  3072x2048 (Wq|Wk|Wv)^T
    u16*  WoT   = (u16*)(ws + 29360128);         //  8 MB  2048x2048
    u16*  Qb    = (u16*)(ws + 37748736);         // 16 MB  (roped, pre-scaled 1/8)
    u16*  KVb   = (u16*)(ws + 54525952);         //  8 MB  4096x1024 (K roped | V)
    u16*  Yb    = (u16*)(ws + 62914560);         // 16 MB
    float* cosT = (float*)(ws + 79691776);       // 256 KB
    float* sinT = (float*)(ws + 79953920);       // 256 KB

    rope_table_kernel<<<dim3(65536 / 256), 256, 0, stream>>>(cosT, sinT);

    cvt_f32_bf16<<<dim3(MROWS * DM / 4 / 256), 256, 0, stream>>>(x, xb, MROWS * DM / 4);

    dim3 tb(32, 8);
    transpose_f32_bf16<<<dim3(2048/32, 2048/32), tb, 0, stream>>>(Wq, WqkvT, 2048, 2048);
    transpose_f32_bf16<<<dim3( 512/32, 2048/32), tb, 0, stream>>>(Wk, WqkvT + 2048 * 2048, 2048, 512);
    transpose_f32_bf16<<<dim3( 512/32, 2048/32), tb, 0, stream>>>(Wv, WqkvT + 2560 * 2048, 2048, 512);
    transpose_f32_bf16<<<dim3(2048/32, 2048/32), tb, 0, stream>>>(Wo, WoT, 2048, 2048);

    gemm_qkv<<<dim3(24, 32), 256, 0, stream>>>(xb, WqkvT, Qb, KVb, cosT, sinT);

    flash_attn<<<dim3(8, NHEADS, 2), 256, 0, stream>>>(Qb, KVb, Yb);

    gemm_out<<<dim3(16, 32), 256, 0, stream>>>(Yb, WoT, out);
}

// Round 8
// 390.504 us; speedup vs baseline: 10.5383x; 1.0261x over previous
//
#include <hip/hip_runtime.h>
#include <cstdint>

typedef unsigned short u16;
typedef __attribute__((ext_vector_type(8))) short short8;   // bf16x8 MFMA frag
typedef __attribute__((ext_vector_type(4))) short short4v;  // bf16x4
typedef __attribute__((ext_vector_type(4))) float f32x4;    // fp32x4 accumulator

#define SEQ     2048
#define NHEADS  32
#define NKV     8
#define HD      64
#define DM      2048
#define MROWS   4096   // BATCH * SEQ
#define KVSTR   1024   // fused KV row stride (8 K-heads | 8 V-heads)
#define PSTR    88     // Ps row stride (u16): 176B, 16B-aligned, 2-way banks

__device__ __forceinline__ float b2f(unsigned int u) {
    return __builtin_bit_cast(float, u << 16);
}
__device__ __forceinline__ u16 f2b(float f) {
    unsigned int u = __builtin_bit_cast(unsigned int, f);
    return (u16)((u + 0x7fffu + ((u >> 16) & 1u)) >> 16);   // RNE
}

// async global->LDS, 16B per lane; LDS dest = wave-uniform base + lane*16
#define GLOAD_LDS16(g, l)                                              \
    __builtin_amdgcn_global_load_lds(                                  \
        (const __attribute__((address_space(1))) void*)(g),            \
        (__attribute__((address_space(3))) void*)(l), 16, 0, 0)

// ------------------------------------------------------------- f32 -> bf16
__global__ __launch_bounds__(256) void cvt_f32_bf16(
    const float* __restrict__ in, u16* __restrict__ out, int n4) {
    int i = blockIdx.x * 256 + threadIdx.x;
    if (i < n4) {
        float4 v = ((const float4*)in)[i];
        ushort4 o;
        o.x = f2b(v.x); o.y = f2b(v.y); o.z = f2b(v.z); o.w = f2b(v.w);
        ((ushort4*)out)[i] = o;
    }
}

// ------------------------------------------------------------- RoPE tables
__global__ __launch_bounds__(256) void rope_table_kernel(
    float* __restrict__ cosT, float* __restrict__ sinT) {
    int idx = blockIdx.x * 256 + threadIdx.x;     // 65536 = 2048*32
    int s  = idx >> 5;
    int dl = idx & 31;
    float inv_freq = exp2f((float)dl * -0.41524101186092025f); // 10000^(-dl/32)
    float ang = (float)s * inv_freq;
    float sn, cs;
    sincosf(ang, &sn, &cs);                        // accurate (range-reduced)
    cosT[idx] = cs;
    sinT[idx] = sn;
}

// ------------------------------------------------- transpose + downcast
__global__ __launch_bounds__(256) void transpose_f32_bf16(
    const float* __restrict__ in, u16* __restrict__ out, int K, int N) {
    __shared__ float tile[32][33];
    int n0 = blockIdx.x * 32, k0 = blockIdx.y * 32;
    int tx = threadIdx.x, ty = threadIdx.y;   // 32 x 8
    for (int r = ty; r < 32; r += 8)
        tile[r][tx] = in[(size_t)(k0 + r) * N + n0 + tx];
    __syncthreads();
    for (int r = ty; r < 32; r += 8)
        out[(size_t)(n0 + r) * K + k0 + tx] = f2b(tile[tx][r]);
}

// ------------------------------------------------------- GEMM core macro
// 128x128 block tile, 4 waves 2x2 (64x64 each, acc 4x4), BK=32, unpadded
// LDS, global_load_lds width=16 (m97 structure).
#define GEMM_BODY(A, BT, Kdim)                                             \
    constexpr int BK = 32;                                                 \
    __shared__ __align__(16) u16 As[128 * BK];                             \
    __shared__ __align__(16) u16 Bs[128 * BK];                             \
    const int tid  = threadIdx.x;                                          \
    const int wid  = tid >> 6;                                             \
    const int lane = tid & 63;                                             \
    const int quad = lane >> 4;                                            \
    const int l16  = lane & 15;                                            \
    const int rowBase = blockIdx.y * 128;                                  \
    const int colBase = blockIdx.x * 128;                                  \
    const int wr = (wid >> 1) * 64;                                        \
    const int wc = (wid & 1) * 64;                                         \
    const int srow = wid * 32 + (lane >> 2);                               \
    const int scol = (lane & 3) * 8;                                       \
    const u16* gA = (A)  + (size_t)(rowBase + srow) * (Kdim) + scol;       \
    const u16* gB = (BT) + (size_t)(colBase + srow) * (Kdim) + scol;       \
    u16* lA0 = &As[(wid * 32) * BK];                                       \
    u16* lA1 = &As[(wid * 32 + 16) * BK];                                  \
    u16* lB0 = &Bs[(wid * 32) * BK];                                       \
    u16* lB1 = &Bs[(wid * 32 + 16) * BK];                                  \
    const size_t row16 = (size_t)16 * (Kdim);                              \
    f32x4 acc[4][4] = {};                                                  \
    for (int k0 = 0; k0 < (Kdim); k0 += BK) {                              \
        GLOAD_LDS16(gA + k0,         lA0);                                 \
        GLOAD_LDS16(gA + k0 + row16, lA1);                                 \
        GLOAD_LDS16(gB + k0,         lB0);                                 \
        GLOAD_LDS16(gB + k0 + row16, lB1);                                 \
        __syncthreads();                                                   \
        short8 a[4], b[4];                                                 \
        _Pragma("unroll")                                                  \
        for (int mi = 0; mi < 4; ++mi)                                     \
            a[mi] = *(const short8*)&As[(wr + mi * 16 + l16) * BK + quad * 8]; \
        _Pragma("unroll")                                                  \
        for (int ni = 0; ni < 4; ++ni)                                     \
            b[ni] = *(const short8*)&Bs[(wc + ni * 16 + l16) * BK + quad * 8]; \
        _Pragma("unroll")                                                  \
        for (int mi = 0; mi < 4; ++mi)                                     \
            _Pragma("unroll")                                              \
            for (int ni = 0; ni < 4; ++ni)                                 \
                acc[mi][ni] = __builtin_amdgcn_mfma_f32_16x16x32_bf16(     \
                    a[mi], b[ni], acc[mi][ni], 0, 0, 0);                   \
        __syncthreads();                                                   \
    }                                                                      \
    const int wRow = rowBase + wr;                                         \
    const int wCol = colBase + wc;

// ------------------------------------------------------- fused QKV GEMM
// C = x @ [Wq | Wk | Wv] (N=3072). Columns: [0,2048) Q -> rope*1/8 -> Qb;
// [2048,2560) K -> rope -> KVb; [2560,3072) V -> plain -> KVb. All branches
// wave-uniform (wCol is 64-aligned, segments 512-aligned).
__global__ __launch_bounds__(256) void gemm_qkv(
    const u16* __restrict__ A, const u16* __restrict__ BT,
    u16* __restrict__ Qb, u16* __restrict__ KVb,
    const float* __restrict__ cosT, const float* __restrict__ sinT) {
    GEMM_BODY(A, BT, DM)

    u16* dst;
    int dstride, dcol;
    float scale;
    bool doRope;
    if (wCol < 2048)      { dst = Qb;  dstride = 2048; dcol = wCol;        scale = 0.125f; doRope = true;  }
    else if (wCol < 2560) { dst = KVb; dstride = 1024; dcol = wCol - 2048; scale = 1.0f;   doRope = true;  }
    else                  { dst = KVb; dstride = 1024; dcol = wCol - 2048; scale = 1.0f;   doRope = false; }

#pragma unroll
    for (int mi = 0; mi < 4; ++mi) {
#pragma unroll
        for (int r = 0; r < 4; ++r) {
            const int R = wRow + mi * 16 + quad * 4 + r;
            u16* crow = dst + (size_t)R * dstride + dcol;
            if (doRope) {
                const int s = R & (SEQ - 1);
#pragma unroll
                for (int ni = 0; ni < 2; ++ni) {
                    const int dl = ni * 16 + l16;           // 0..31
                    float lo = acc[mi][ni][r];
                    float hi = acc[mi][ni + 2][r];
                    float cs = cosT[s * 32 + dl];
                    float sn = sinT[s * 32 + dl];
                    crow[dl]      = f2b((lo * cs - hi * sn) * scale);
                    crow[dl + 32] = f2b((hi * cs + lo * sn) * scale);
                }
            } else {
#pragma unroll
                for (int ni = 0; ni < 4; ++ni)
                    crow[ni * 16 + l16] = f2b(acc[mi][ni][r]);
            }
        }
    }
}

// ------------------------------------------------------- output GEMM (f32)
__global__ __launch_bounds__(256) void gemm_out(
    const u16* __restrict__ A, const u16* __restrict__ BT,
    float* __restrict__ C32) {
    GEMM_BODY(A, BT, DM)
#pragma unroll
    for (int mi = 0; mi < 4; ++mi) {
#pragma unroll
        for (int r = 0; r < 4; ++r) {
            const int R = wRow + mi * 16 + quad * 4 + r;
            float* crow = C32 + (size_t)R * DM + wCol;
#pragma unroll
            for (int ni = 0; ni < 4; ++ni)
                crow[ni * 16 + l16] = acc[mi][ni][r];
        }
    }
}

// ------------------------------------------------------- flash attention
// 512 threads = 8 waves; wave w owns 16 q-rows (one 16-row M-tile) of the
// current 128-row q-tile. Triangle pairing {bx, 15-bx} -> uniform 36
// key-tiles/block. Grid (8,32,2)=512 blocks -> 16 waves/CU (2 blocks/CU by
// LDS), double round-7's 8 waves/CU: the r5->r6 scaling showed this kernel
// is latency-bound and scales ~linearly with occupancy.
__global__ __launch_bounds__(512, 4) void flash_attn(
    const u16* __restrict__ Q, const u16* __restrict__ KV,
    u16* __restrict__ Y) {
    __shared__ __align__(16) u16 Ks[64 * 64];         // 8 KB, XOR-swizzled
    __shared__ __align__(16) u16 Vt[64 * 72];         // 9 KB, [dim][key]
    __shared__ __align__(16) u16 Ps[8 * 16 * PSTR];   // 22 KB

    const int h   = blockIdx.y;
    const int b   = blockIdx.z;
    const int kvh = h >> 2;
    const int tid  = threadIdx.x;
    const int wid  = tid >> 6;          // 0..7
    const int lane = tid & 63;
    const int quad = lane >> 4;
    const int l16  = lane & 15;

    const u16* Kg = KV + (size_t)b * SEQ * KVSTR + kvh * HD;
    const u16* Vg = Kg + 512;
    u16* Psw = Ps + wid * 16 * PSTR;

    // staging coords (512 threads)
    const int kKey = tid >> 3, kCc = tid & 7;   // K: one 16B chunk/thread
    const int vkp  = tid & 31;                  // V: key pair 2vkp, 2vkp+1
    const int vd0  = (tid >> 5) * 4;            // 4 dims

    for (int half = 0; half < 2; ++half) {
        const int qt = half ? (15 - blockIdx.x) : blockIdx.x;
        const int rowBaseW = qt * 128 + wid * 16;

        // --- preload Q A-frags (Q pre-scaled by 1/8 in GEMM epilogue)
        short8 qf[2];
#pragma unroll
        for (int ks = 0; ks < 2; ++ks)
            qf[ks] = *(const short8*)&Q[
                (size_t)(b * SEQ + rowBaseW + l16) * (NHEADS * HD)
                + h * HD + ks * 32 + quad * 8];

        f32x4 o[4] = {};
        float mi[4], li[4];
#pragma unroll
        for (int r = 0; r < 4; ++r) { mi[r] = -3e38f; li[r] = 0.f; }

        const int nTiles = 2 * qt + 2;

        // --- prefetch tile 0
        short8  kreg = *(const short8*)&Kg[(size_t)kKey * KVSTR + kCc * 8];
        short4v vrA  = *(const short4v*)&Vg[(size_t)(2 * vkp)     * KVSTR + vd0];
        short4v vrB  = *(const short4v*)&Vg[(size_t)(2 * vkp + 1) * KVSTR + vd0];

        for (int t = 0; t < nTiles; ++t) {
            const int j0 = t * 64;
            __syncthreads();   // previous tile's LDS reads done

            // --- write staged K (XOR-swizzled 16B chunks)
            *(short8*)&Ks[kKey * 64 + ((kCc ^ (kKey & 7)) * 8)] = kreg;
            // --- write staged V as packed key-pairs (4 x b32, conflict-free)
#pragma unroll
            for (int i = 0; i < 4; ++i) {
                unsigned int w = (unsigned int)(u16)vrA[i]
                               | ((unsigned int)(u16)vrB[i] << 16);
                ((unsigned int*)Vt)[(vd0 + i) * 36 + vkp] = w;
            }
            __syncthreads();

            // --- prefetch tile t+1 (overlaps with compute below)
            if (t + 1 < nTiles) {
                const size_t jn = (size_t)(j0 + 64);
                kreg = *(const short8*)&Kg[(jn + kKey) * KVSTR + kCc * 8];
                vrA  = *(const short4v*)&Vg[(jn + 2 * vkp)     * KVSTR + vd0];
                vrB  = *(const short4v*)&Vg[(jn + 2 * vkp + 1) * KVSTR + vd0];
            }

            // --- S = Q @ K^T  (8 MFMA)
            f32x4 s[4] = {};
#pragma unroll
            for (int ks = 0; ks < 2; ++ks)
#pragma unroll
                for (int ct = 0; ct < 4; ++ct) {
                    int key = ct * 16 + l16;
                    int cc  = (ks * 4 + quad) ^ (key & 7);
                    short8 bk = *(const short8*)&Ks[key * 64 + cc * 8];
                    s[ct] = __builtin_amdgcn_mfma_f32_16x16x32_bf16(
                        qf[ks], bk, s[ct], 0, 0, 0);
                }

            // --- causal mask (gate vs wave MIN row — round-4 lesson)
            if (j0 + 63 > rowBaseW) {
#pragma unroll
                for (int ct = 0; ct < 4; ++ct)
#pragma unroll
                    for (int r = 0; r < 4; ++r) {
                        int R = rowBaseW + quad * 4 + r;
                        int J = j0 + ct * 16 + l16;
                        if (J > R) s[ct][r] = -3e38f;
                    }
            }

            // --- online softmax (rows = quad*4+r, reduce over l16)
#pragma unroll
            for (int r = 0; r < 4; ++r) {
                float rmax = fmaxf(fmaxf(s[0][r], s[1][r]),
                                   fmaxf(s[2][r], s[3][r]));
                rmax = fmaxf(rmax, __shfl_xor(rmax, 1, 64));
                rmax = fmaxf(rmax, __shfl_xor(rmax, 2, 64));
                rmax = fmaxf(rmax, __shfl_xor(rmax, 4, 64));
                rmax = fmaxf(rmax, __shfl_xor(rmax, 8, 64));
                float mnew  = fmaxf(mi[r], rmax);
                float alpha = __expf(mi[r] - mnew);
                mi[r] = mnew;
                float rs = 0.f;
#pragma unroll
                for (int ct = 0; ct < 4; ++ct) {
                    float p = __expf(s[ct][r] - mnew);
                    s[ct][r] = p;
                    rs += p;
                    o[ct][r] *= alpha;
                }
                rs += __shfl_xor(rs, 1, 64);
                rs += __shfl_xor(rs, 2, 64);
                rs += __shfl_xor(rs, 4, 64);
                rs += __shfl_xor(rs, 8, 64);
                li[r] = li[r] * alpha + rs;
            }

            // --- P: C-layout -> LDS -> A-layout (wave-private)
#pragma unroll
            for (int ct = 0; ct < 4; ++ct)
#pragma unroll
                for (int r = 0; r < 4; ++r)
                    Psw[(quad * 4 + r) * PSTR + ct * 16 + l16] = f2b(s[ct][r]);

            // --- O += P @ V  (8 MFMA)
            short8 pa[2];
#pragma unroll
            for (int ks = 0; ks < 2; ++ks)
                pa[ks] = *(const short8*)&Psw[l16 * PSTR + ks * 32 + quad * 8];
#pragma unroll
            for (int ks = 0; ks < 2; ++ks)
#pragma unroll
                for (int ct = 0; ct < 4; ++ct) {
                    short8 vbf = *(const short8*)&Vt[(ct * 16 + l16) * 72 + ks * 32 + quad * 8];
                    o[ct] = __builtin_amdgcn_mfma_f32_16x16x32_bf16(
                        pa[ks], vbf, o[ct], 0, 0, 0);
                }
        }

        // --- normalize + store this half's q-tile
        float rli[4];
#pragma unroll
        for (int r = 0; r < 4; ++r) rli[r] = 1.0f / li[r];
#pragma unroll
        for (int r = 0; r < 4; ++r) {
            int R = rowBaseW + quad * 4 + r;
            u16* yrow = Y + (size_t)(b * SEQ + R) * (NHEADS * HD) + h * HD;
#pragma unroll
            for (int ct = 0; ct < 4; ++ct)
                yrow[ct * 16 + l16] = f2b(o[ct][r] * rli[r]);
        }
    }
}

// ---------------------------------------------------------------- launch
extern "C" void kernel_launch(void* const* d_in, const int* in_sizes, int n_in,
                              void* d_out, int out_size, void* d_ws, size_t ws_size,
                              hipStream_t stream) {
    const float* x  = (const float*)d_in[0];
    const float* Wq = (const float*)d_in[1];
    const float* Wk = (const float*)d_in[2];
    const float* Wv = (const float*)d_in[3];
    const float* Wo = (const float*)d_in[4];
    float* out = (float*)d_out;   // f32 output

    char* ws = (char*)d_ws;
    u16*  xb    = (u16*)(ws);                    // 16 MB  4096x2048 bf16
    u16*  WqkvT = (u16*)(ws + 16777216);         // 12 MB  3072x2048 (Wq|Wk|Wv)^T
    u16*  WoT   = (u16*)(ws + 29360128);         //  8 MB  2048x2048
    u16*  Qb    = (u16*)(ws + 37748736);         // 16 MB  (roped, pre-scaled 1/8)
    u16*  KVb   = (u16*)(ws + 54525952);         //  8 MB  4096x1024 (K roped | V)
    u16*  Yb    = (u16*)(ws + 62914560);         // 16 MB
    float* cosT = (float*)(ws + 79691776);       // 256 KB
    float* sinT = (float*)(ws + 79953920);       // 256 KB

    rope_table_kernel<<<dim3(65536 / 256), 256, 0, stream>>>(cosT, sinT);

    cvt_f32_bf16<<<dim3(MROWS * DM / 4 / 256), 256, 0, stream>>>(x, xb, MROWS * DM / 4);

    dim3 tb(32, 8);
    transpose_f32_bf16<<<dim3(2048/32, 2048/32), tb, 0, stream>>>(Wq, WqkvT, 2048, 2048);
    transpose_f32_bf16<<<dim3( 512/32, 2048/32), tb, 0, stream>>>(Wk, WqkvT + 2048 * 2048, 2048, 512);
    transpose_f32_bf16<<<dim3( 512/32, 2048/32), tb, 0, stream>>>(Wv, WqkvT + 2560 * 2048, 2048, 512);
    transpose_f32_bf16<<<dim3(2048/32, 2048/32), tb, 0, stream>>>(Wo, WoT, 2048, 2048);

    gemm_qkv<<<dim3(24, 32), 256, 0, stream>>>(xb, WqkvT, Qb, KVb, cosT, sinT);

    flash_attn<<<dim3(8, NHEADS, 2), 512, 0, stream>>>(Qb, KVb, Yb);

    gemm_out<<<dim3(16, 32), 256, 0, stream>>>(Yb, WoT, out);
}